// Round 9
// baseline (332.278 us; speedup 1.0000x reference)
//
#include <hip/hip_runtime.h>

#define S_LEN 1024
#define B_SZ 8
#define F_IN_D 256
#define E_DIM 512
#define INNER_D 1024
#define NH_D 4
#define DH_D 256
#define NROW (B_SZ * S_LEN)   // 8192

typedef _Float16 half8 __attribute__((ext_vector_type(8)));
typedef _Float16 half4_t __attribute__((ext_vector_type(4)));
typedef float v4f __attribute__((ext_vector_type(4)));
typedef float v16f __attribute__((ext_vector_type(16)));

// ---------------------------------------------------------------------------
// Cast 4 f32 buffers to f16 in one pass (x, W_in, W_up, W_down).
// ---------------------------------------------------------------------------
__global__ __launch_bounds__(256) void cast4_kernel(
    const float* __restrict__ s0, const float* __restrict__ s1,
    const float* __restrict__ s2, const float* __restrict__ s3,
    _Float16* __restrict__ d0, _Float16* __restrict__ d1,
    _Float16* __restrict__ d2, _Float16* __restrict__ d3,
    int n0, int n1, int n2, int n3)
{
  int i = (blockIdx.x * 256 + threadIdx.x) * 4;
  const float* s; _Float16* d; int off;
  if (i < n0)                { s = s0; d = d0; off = i; }
  else if (i < n0 + n1)      { s = s1; d = d1; off = i - n0; }
  else if (i < n0 + n1 + n2) { s = s2; d = d2; off = i - n0 - n1; }
  else if (i < n0 + n1 + n2 + n3) { s = s3; d = d3; off = i - n0 - n1 - n2; }
  else return;
  float4 v = *(const float4*)(s + off);
  half4_t o = {(_Float16)v.x, (_Float16)v.y, (_Float16)v.z, (_Float16)v.w};
  *(half4_t*)(d + off) = o;
}

// ---------------------------------------------------------------------------
// Pure-f16 MFMA NT GEMM: C[M,N] = A[M,K] @ B[N,K]^T (+ bias), C f32.
// ---------------------------------------------------------------------------
#define GBM 128
#define GBN 128
#define GBK 32
#define LDKG (GBK + 8)

__global__ __launch_bounds__(256) void gemm_h16(
    const _Float16* __restrict__ A, const _Float16* __restrict__ B,
    const float* __restrict__ bias, float* __restrict__ C,
    int M, int N, int K)
{
  __shared__ __align__(16) _Float16 As[GBM][LDKG];
  __shared__ __align__(16) _Float16 Bs[GBN][LDKG];
  const int tid = threadIdx.x;
  const int lane = tid & 63, w = tid >> 6;
  const int wr = w >> 1, wc = w & 1;
  const int quad = lane >> 4, l16 = lane & 15;
  const int bm = blockIdx.y * GBM, bn = blockIdx.x * GBN;
  const int srow = tid >> 1;
  const int scol = (tid & 1) * 16;

  v4f acc[4][4];
#pragma unroll
  for (int i = 0; i < 4; ++i)
#pragma unroll
    for (int j = 0; j < 4; ++j) acc[i][j] = (v4f){0.f, 0.f, 0.f, 0.f};

  const _Float16* Ap = A + (size_t)(bm + srow) * K + scol;
  const _Float16* Bp = B + (size_t)(bn + srow) * K + scol;
  half8 a0 = *(const half8*)(Ap);
  half8 a1 = *(const half8*)(Ap + 8);
  half8 b0 = *(const half8*)(Bp);
  half8 b1 = *(const half8*)(Bp + 8);

  for (int k0 = 0; k0 < K; k0 += GBK) {
    __syncthreads();
    *(half8*)(&As[srow][scol]) = a0;
    *(half8*)(&As[srow][scol + 8]) = a1;
    *(half8*)(&Bs[srow][scol]) = b0;
    *(half8*)(&Bs[srow][scol + 8]) = b1;
    __syncthreads();
    if (k0 + GBK < K) {
      const int kn = k0 + GBK;
      a0 = *(const half8*)(Ap + kn);
      a1 = *(const half8*)(Ap + kn + 8);
      b0 = *(const half8*)(Bp + kn);
      b1 = *(const half8*)(Bp + kn + 8);
    }
    half8 af[4], bf[4];
#pragma unroll
    for (int i = 0; i < 4; ++i)
      af[i] = *(const half8*)(&As[wr * 64 + i * 16 + l16][quad * 8]);
#pragma unroll
    for (int j = 0; j < 4; ++j)
      bf[j] = *(const half8*)(&Bs[wc * 64 + j * 16 + l16][quad * 8]);
#pragma unroll
    for (int i = 0; i < 4; ++i)
#pragma unroll
      for (int j = 0; j < 4; ++j)
        acc[i][j] = __builtin_amdgcn_mfma_f32_16x16x32_f16(af[i], bf[j], acc[i][j], 0, 0, 0);
  }

#pragma unroll
  for (int j = 0; j < 4; ++j) {
    const int col = bn + wc * 64 + j * 16 + l16;
    const float bv = bias ? bias[col] : 0.f;
#pragma unroll
    for (int i = 0; i < 4; ++i) {
      const int row0 = bm + wr * 64 + i * 16 + quad * 4;
#pragma unroll
      for (int r = 0; r < 4; ++r)
        C[(size_t)(row0 + r) * N + col] = acc[i][j][r] + bv;
    }
  }
}

// ---------------------------------------------------------------------------
// Up-projection GEMM: writes x_m half as f16 (xmh) and silu(z) f16 (szb).
// ---------------------------------------------------------------------------
__global__ __launch_bounds__(256) void gemm_h16_up(
    const _Float16* __restrict__ A, const _Float16* __restrict__ B,
    _Float16* __restrict__ xmh, _Float16* __restrict__ szb,
    int M, int N, int K)
{
  __shared__ __align__(16) _Float16 As[GBM][LDKG];
  __shared__ __align__(16) _Float16 Bs[GBN][LDKG];
  const int tid = threadIdx.x;
  const int lane = tid & 63, w = tid >> 6;
  const int wr = w >> 1, wc = w & 1;
  const int quad = lane >> 4, l16 = lane & 15;
  const int bm = blockIdx.y * GBM, bn = blockIdx.x * GBN;
  const int srow = tid >> 1;
  const int scol = (tid & 1) * 16;

  v4f acc[4][4];
#pragma unroll
  for (int i = 0; i < 4; ++i)
#pragma unroll
    for (int j = 0; j < 4; ++j) acc[i][j] = (v4f){0.f, 0.f, 0.f, 0.f};

  const _Float16* Ap = A + (size_t)(bm + srow) * K + scol;
  const _Float16* Bp = B + (size_t)(bn + srow) * K + scol;
  half8 a0 = *(const half8*)(Ap);
  half8 a1 = *(const half8*)(Ap + 8);
  half8 b0 = *(const half8*)(Bp);
  half8 b1 = *(const half8*)(Bp + 8);

  for (int k0 = 0; k0 < K; k0 += GBK) {
    __syncthreads();
    *(half8*)(&As[srow][scol]) = a0;
    *(half8*)(&As[srow][scol + 8]) = a1;
    *(half8*)(&Bs[srow][scol]) = b0;
    *(half8*)(&Bs[srow][scol + 8]) = b1;
    __syncthreads();
    if (k0 + GBK < K) {
      const int kn = k0 + GBK;
      a0 = *(const half8*)(Ap + kn);
      a1 = *(const half8*)(Ap + kn + 8);
      b0 = *(const half8*)(Bp + kn);
      b1 = *(const half8*)(Bp + kn + 8);
    }
    half8 af[4], bf[4];
#pragma unroll
    for (int i = 0; i < 4; ++i)
      af[i] = *(const half8*)(&As[wr * 64 + i * 16 + l16][quad * 8]);
#pragma unroll
    for (int j = 0; j < 4; ++j)
      bf[j] = *(const half8*)(&Bs[wc * 64 + j * 16 + l16][quad * 8]);
#pragma unroll
    for (int i = 0; i < 4; ++i)
#pragma unroll
      for (int j = 0; j < 4; ++j)
        acc[i][j] = __builtin_amdgcn_mfma_f32_16x16x32_f16(af[i], bf[j], acc[i][j], 0, 0, 0);
  }

  const bool zhalf = (bn >= INNER_D);
#pragma unroll
  for (int j = 0; j < 4; ++j) {
    const int col = bn + wc * 64 + j * 16 + l16;
    const int colm = col & (INNER_D - 1);
#pragma unroll
    for (int i = 0; i < 4; ++i) {
      const int row0 = bm + wr * 64 + i * 16 + quad * 4;
#pragma unroll
      for (int r = 0; r < 4; ++r) {
        float a = acc[i][j][r];
        if (zhalf) {
          float s = a / (1.f + __expf(-a));
          szb[(size_t)(row0 + r) * INNER_D + colm] = (_Float16)s;
        } else {
          xmh[(size_t)(row0 + r) * INNER_D + colm] = (_Float16)a;
        }
      }
    }
  }
}

// ---------------------------------------------------------------------------
__device__ __forceinline__ float block_sum4(float v, float* red, int tid) {
#pragma unroll
  for (int off = 32; off; off >>= 1) v += __shfl_xor(v, off);
  if ((tid & 63) == 0) red[tid >> 6] = v;
  __syncthreads();
  float t = red[0] + red[1] + red[2] + red[3];
  __syncthreads();
  return t;
}

__global__ __launch_bounds__(256) void ln_mul_kernel(
    const float* __restrict__ in, const float* __restrict__ w,
    _Float16* __restrict__ out)
{
  __shared__ float red[4];
  const int row = blockIdx.x;
  const int tid = threadIdx.x;
  const float* p = in + (size_t)row * E_DIM;
  float v0 = p[tid], v1 = p[tid + 256];
  float mean = block_sum4(v0 + v1, red, tid) * (1.f / E_DIM);
  float d0 = v0 - mean, d1 = v1 - mean;
  float var = block_sum4(d0 * d0 + d1 * d1, red, tid) * (1.f / E_DIM);
  float rstd = rsqrtf(var + 1e-5f);
  out[(size_t)row * E_DIM + tid] = (_Float16)(d0 * rstd * w[tid]);
  out[(size_t)row * E_DIM + tid + 256] = (_Float16)(d1 * rstd * w[tid + 256]);
}

__global__ __launch_bounds__(256) void final_ln_kernel(
    const float* __restrict__ res, const float* __restrict__ y,
    const float* __restrict__ w, float* __restrict__ out)
{
  __shared__ float red[4];
  const int row = blockIdx.x;
  const int tid = threadIdx.x;
  const size_t base = (size_t)row * E_DIM;
  float v0 = res[base + tid] + y[base + tid];
  float v1 = res[base + tid + 256] + y[base + tid + 256];
  float mean = block_sum4(v0 + v1, red, tid) * (1.f / E_DIM);
  float d0 = v0 - mean, d1 = v1 - mean;
  float var = block_sum4(d0 * d0 + d1 * d1, red, tid) * (1.f / E_DIM);
  float rstd = rsqrtf(var + 1e-5f);
  out[base + tid] = d0 * rstd * w[tid];
  out[base + tid + 256] = d1 * rstd * w[tid + 256];
}

// ---------------------------------------------------------------------------
// Fused conv+silu + headwise q/k/v + gates, 4 rows per block.
// ---------------------------------------------------------------------------
__global__ __launch_bounds__(256) void chg_kernel(
    const _Float16* __restrict__ xm, const float* __restrict__ cw,
    const float* __restrict__ cb,
    const float* __restrict__ Wq, const float* __restrict__ Wk,
    const float* __restrict__ Wv,
    const float* __restrict__ Wig, const float* __restrict__ big,
    const float* __restrict__ Wfg, const float* __restrict__ bfg,
    _Float16* __restrict__ xch, _Float16* __restrict__ qh,
    _Float16* __restrict__ khb, _Float16* __restrict__ vhb,
    float* __restrict__ ig, float* __restrict__ fg)
{
  __shared__ float red[4][32];
  const int tid = threadIdx.x;
  const int lane = tid & 63, wid = tid >> 6;
  const int row0 = blockIdx.x * 4;
  const int sl0 = row0 & (S_LEN - 1);
  const int c = tid * 4;

  float t[7][4];
#pragma unroll
  for (int j = 0; j < 7; ++j) {
    const int off = j - 3;
    if (sl0 + off < 0) {
      t[j][0] = t[j][1] = t[j][2] = t[j][3] = 0.f;
    } else {
      half4_t hv = *(const half4_t*)(xm + (size_t)(row0 + off) * INNER_D + c);
      t[j][0] = (float)hv.x; t[j][1] = (float)hv.y;
      t[j][2] = (float)hv.z; t[j][3] = (float)hv.w;
    }
  }
  float wct[4][4];
#pragma unroll
  for (int j = 0; j < 4; ++j) {
    float4 wc4 = *(const float4*)(cw + (c + j) * 4);
    wct[j][0] = wc4.x; wct[j][1] = wc4.y; wct[j][2] = wc4.z; wct[j][3] = wc4.w;
  }
  float4 cb4 = *(const float4*)(cb + c);
  const float cbs[4] = {cb4.x, cb4.y, cb4.z, cb4.w};
  float wqm[16], wkm[16], wvm[16];
#pragma unroll
  for (int i = 0; i < 4; ++i) {
    float4 a = *(const float4*)(Wq + tid * 16 + i * 4);
    float4 bq = *(const float4*)(Wk + tid * 16 + i * 4);
    float4 cq = *(const float4*)(Wv + tid * 16 + i * 4);
    wqm[i * 4] = a.x; wqm[i * 4 + 1] = a.y; wqm[i * 4 + 2] = a.z; wqm[i * 4 + 3] = a.w;
    wkm[i * 4] = bq.x; wkm[i * 4 + 1] = bq.y; wkm[i * 4 + 2] = bq.z; wkm[i * 4 + 3] = bq.w;
    wvm[i * 4] = cq.x; wvm[i * 4 + 1] = cq.y; wvm[i * 4 + 2] = cq.z; wvm[i * 4 + 3] = cq.w;
  }

  float q4[4][4], k4[4][4], v4m[4][4];
#pragma unroll
  for (int r = 0; r < 4; ++r) {
    float xc4[4];
#pragma unroll
    for (int j = 0; j < 4; ++j) {
      float a = cbs[j] + wct[j][0] * t[r][j] + wct[j][1] * t[r + 1][j]
                       + wct[j][2] * t[r + 2][j] + wct[j][3] * t[r + 3][j];
      xc4[j] = a / (1.f + __expf(-a));
    }
#pragma unroll
    for (int i = 0; i < 4; ++i) {
      q4[r][i] = wqm[i * 4] * xc4[0] + wqm[i * 4 + 1] * xc4[1]
               + wqm[i * 4 + 2] * xc4[2] + wqm[i * 4 + 3] * xc4[3];
      k4[r][i] = wkm[i * 4] * xc4[0] + wkm[i * 4 + 1] * xc4[1]
               + wkm[i * 4 + 2] * xc4[2] + wkm[i * 4 + 3] * xc4[3];
      v4m[r][i] = wvm[i * 4] * t[r + 3][0] + wvm[i * 4 + 1] * t[r + 3][1]
                + wvm[i * 4 + 2] * t[r + 3][2] + wvm[i * 4 + 3] * t[r + 3][3];
    }
    const size_t base = (size_t)(row0 + r) * INNER_D + c;
    half4_t xo = {(_Float16)xc4[0], (_Float16)xc4[1], (_Float16)xc4[2], (_Float16)xc4[3]};
    half4_t qo = {(_Float16)q4[r][0], (_Float16)q4[r][1], (_Float16)q4[r][2], (_Float16)q4[r][3]};
    half4_t ko = {(_Float16)k4[r][0], (_Float16)k4[r][1], (_Float16)k4[r][2], (_Float16)k4[r][3]};
    half4_t vo = {(_Float16)v4m[r][0], (_Float16)v4m[r][1], (_Float16)v4m[r][2], (_Float16)v4m[r][3]};
    *(half4_t*)(xch + base) = xo;
    *(half4_t*)(qh + base) = qo;
    *(half4_t*)(khb + base) = ko;
    *(half4_t*)(vhb + base) = vo;
  }

  float vals[32];
#pragma unroll
  for (int g = 0; g < 8; ++g) {
    const float* wb = (g < 4 ? Wig : Wfg) + (g & 3) * 3072 + c;
    float4 w1 = *(const float4*)(wb);
    float4 w2 = *(const float4*)(wb + 1024);
    float4 w3 = *(const float4*)(wb + 2048);
#pragma unroll
    for (int r = 0; r < 4; ++r) {
      vals[g * 4 + r] =
          q4[r][0] * w1.x + q4[r][1] * w1.y + q4[r][2] * w1.z + q4[r][3] * w1.w
        + k4[r][0] * w2.x + k4[r][1] * w2.y + k4[r][2] * w2.z + k4[r][3] * w2.w
        + v4m[r][0] * w3.x + v4m[r][1] * w3.y + v4m[r][2] * w3.z + v4m[r][3] * w3.w;
    }
  }
#pragma unroll
  for (int i = 0; i < 32; ++i) {
    float x = vals[i];
#pragma unroll
    for (int off = 32; off; off >>= 1) x += __shfl_xor(x, off);
    vals[i] = x;
  }
  if (lane == 0) {
#pragma unroll
    for (int i = 0; i < 32; ++i) red[wid][i] = vals[i];
  }
  __syncthreads();
  if (tid < 32) {
    float sm = red[0][tid] + red[1][tid] + red[2][tid] + red[3][tid];
    const int g = tid >> 2, r = tid & 3;
    const int h = g & 3;
    const int b = row0 >> 10;
    const size_t oidx = (size_t)(b * NH_D + h) * S_LEN + sl0 + r;
    if (g < 4) ig[oidx] = sm + big[h];
    else       fg[oidx] = sm + bfg[h];
  }
}

// ---------------------------------------------------------------------------
__device__ __forceinline__ float logsigf(float x) {
  return fminf(x, 0.f) - log1pf(__expf(-fabsf(x)));
}

__global__ __launch_bounds__(256) void scan_kernel(
    const float* __restrict__ ig, const float* __restrict__ fg,
    float* __restrict__ m_, float* __restrict__ rmax_, float* __restrict__ maxd_,
    float* __restrict__ em_)
{
  __shared__ float sc[256];
  const int bh = blockIdx.x;
  const int tid = threadIdx.x;
  const size_t base = (size_t)bh * S_LEN + tid * 4;
  float4 f4 = *(const float4*)(fg + base);
  float4 i4 = *(const float4*)(ig + base);
  float l0 = logsigf(f4.x), l1 = logsigf(f4.y), l2 = logsigf(f4.z), l3 = logsigf(f4.w);
  float p0 = l0, p1 = p0 + l1, p2 = p1 + l2, p3 = p2 + l3;
  sc[tid] = p3;
  __syncthreads();
  for (int off = 1; off < 256; off <<= 1) {
    float o = (tid >= off) ? sc[tid - off] : 0.f;
    __syncthreads();
    sc[tid] += o;
    __syncthreads();
  }
  float aoff = (tid == 0) ? 0.f : sc[tid - 1];
  __syncthreads();
  float a0 = aoff + p0, a1 = aoff + p1, a2 = aoff + p2, a3 = aoff + p3;
  float m0 = i4.x - a0, m1 = i4.y - a1, m2 = i4.z - a2, m3 = i4.w - a3;
  float x0 = m0, x1 = fmaxf(x0, m1), x2 = fmaxf(x1, m2), x3 = fmaxf(x2, m3);
  sc[tid] = x3;
  __syncthreads();
  for (int off = 1; off < 256; off <<= 1) {
    float o = (tid >= off) ? sc[tid - off] : -1e30f;
    __syncthreads();
    sc[tid] = fmaxf(sc[tid], o);
    __syncthreads();
  }
  float moff = (tid == 0) ? -1e30f : sc[tid - 1];
  float tmax = sc[tid | 15];
  float r0 = fmaxf(moff, x0), r1 = fmaxf(moff, x1), r2 = fmaxf(moff, x2), r3 = fmaxf(moff, x3);
  const float scale = 0.0625f;
  float4 mo = {m0, m1, m2, m3};
  float4 ro = {r0, r1, r2, r3};
  float4 dd = {a0 + r0, a1 + r1, a2 + r2, a3 + r3};
  float4 eo = {scale * __expf(m0 - tmax), scale * __expf(m1 - tmax),
               scale * __expf(m2 - tmax), scale * __expf(m3 - tmax)};
  *(float4*)(m_ + base) = mo;
  *(float4*)(rmax_ + base) = ro;
  *(float4*)(maxd_ + base) = dd;
  *(float4*)(em_ + base) = eo;
}

// ---------------------------------------------------------------------------
__global__ __launch_bounds__(256) void vtrans_kernel(
    const _Float16* __restrict__ vb, _Float16* __restrict__ vt)
{
  __shared__ _Float16 tile[64][68];
  const int b = blockIdx.z, dt = blockIdx.x, st = blockIdx.y;
  const int c4 = (threadIdx.x & 15) * 4, rr = threadIdx.x >> 4;
  const int s0 = st * 64, d0 = dt * 64;
#pragma unroll
  for (int i = 0; i < 4; ++i) {
    int r = rr + i * 16;
    half4_t v = *(const half4_t*)(vb + ((size_t)(b * S_LEN + s0 + r)) * INNER_D + d0 + c4);
    tile[r][c4 + 0] = v.x; tile[r][c4 + 1] = v.y;
    tile[r][c4 + 2] = v.z; tile[r][c4 + 3] = v.w;
  }
  __syncthreads();
#pragma unroll
  for (int i = 0; i < 4; ++i) {
    int dd = rr + i * 16;
    half4_t o = {tile[c4 + 0][dd], tile[c4 + 1][dd], tile[c4 + 2][dd], tile[c4 + 3][dd]};
    *(half4_t*)(vt + ((size_t)(b * INNER_D + d0 + dd)) * S_LEN + s0 + c4) = o;
  }
}

// ---------------------------------------------------------------------------
// 32x32-MFMA attention. Block = 4 waves = 2 pairs; pair owns 32 s-rows.
// Within a pair: wave hw computes QK t-half (one 32x32 C, 16 mfma/tile) and
// PV d-half (4x 32x32 acc, 16 mfma/tile). Halves LDS bytes/FLOP vs 16x16.
// C/D: col=lane&31, row=(reg&3)+8(reg>>2)+4(lane>>5); A/B: m|n=lane&31,
// k=(lane>>5)*8+j.
// ---------------------------------------------------------------------------
#define KP 264
#define VP 72

__global__ __launch_bounds__(256, 2) void attn32_kernel(
    const _Float16* __restrict__ qh, const _Float16* __restrict__ khb,
    const _Float16* __restrict__ vt,
    const float* __restrict__ m_, const float* __restrict__ em,
    const float* __restrict__ rmax_, const float* __restrict__ maxd_,
    const float* __restrict__ mhln_w, const float* __restrict__ skip,
    const _Float16* __restrict__ xch, const _Float16* __restrict__ szb,
    _Float16* __restrict__ hstate)
{
  __shared__ __align__(16) _Float16 Ks[64][KP];          // 33.8 KB
  __shared__ __align__(16) _Float16 Vs[256][VP];         // 36.9 KB
  __shared__ __align__(16) _Float16 plds[2][32][72];     // 9.2 KB (reused in epilogue)
  float* redb = (float*)plds;   // epilogue reduction buffer [4][32]

  const int tid = threadIdx.x;
  const int lane = tid & 63, wid = tid >> 6;
  const int pair = wid >> 1, hw = wid & 1;
  const int l31 = lane & 31, hl = lane >> 5;
  const int bh = blockIdx.x & 31;
  const int pp = blockIdx.x >> 5;
  const int sblk = 15 - pp;
  const int h = bh & 3, b = bh >> 2;
  const float* rmaxp = rmax_ + (size_t)bh * S_LEN;
  const float* emp = em + (size_t)bh * S_LEN;
  const float* mp = m_ + (size_t)bh * S_LEN;
  const float* maxdp = maxd_ + (size_t)bh * S_LEN;
  const float scale = 0.0625f;

  const _Float16* kg = khb + ((size_t)(b * S_LEN)) * INNER_D + h * DH_D;
  const _Float16* vg = vt + ((size_t)(b * INNER_D + h * DH_D)) * S_LEN;
  const int krow_s = tid >> 5;
  const int kcol_s = (tid & 31) * 8;
  const int vrow_s = tid >> 3;
  const int vcol_s = (tid & 7) * 8;

  const int ntile = sblk + 1;
  const int s0 = sblk * 64 + pair * 32;     // pair's first global s-row

  int rowl[16];
#pragma unroll
  for (int i = 0; i < 16; ++i) rowl[i] = (i & 3) + 8 * (i >> 2) + 4 * hl;

  // stage tile 0
  half8 kpre[8], vpre[8];
#pragma unroll
  for (int i = 0; i < 8; ++i) {
    kpre[i] = *(const half8*)(kg + (size_t)(i * 8 + krow_s) * INNER_D + kcol_s);
    vpre[i] = *(const half8*)(vg + (size_t)(i * 32 + vrow_s) * S_LEN + vcol_s);
  }

  // Q fragments: A[m=l31][k=kc*16 + hl*8 + j], 16 chunks
  half8 qf[16];
  const _Float16* qrow = qh + ((size_t)(b * S_LEN + s0 + l31)) * INNER_D + h * DH_D + hl * 8;
#pragma unroll
  for (int kc = 0; kc < 16; ++kc) qf[kc] = *(const half8*)(qrow + kc * 16);

  v16f acc[4];
#pragma unroll
  for (int dt = 0; dt < 4; ++dt) acc[dt] = (v16f)(0.f);
  float rsum[16];
#pragma unroll
  for (int i = 0; i < 16; ++i) rsum[i] = 0.f;
  float rmax_row[16];
#pragma unroll
  for (int i = 0; i < 16; ++i) rmax_row[i] = rmaxp[s0 + rowl[i]];

  const int tloc = hw * 32 + l31;           // this wave's QK column within tile

  for (int tt = 0; tt < ntile; ++tt) {
    const int t0 = tt * 64;
    const bool last = (tt + 1 == ntile);
    __syncthreads();
#pragma unroll
    for (int i = 0; i < 8; ++i) {
      *(half8*)(&Ks[i * 8 + krow_s][kcol_s]) = kpre[i];
      *(half8*)(&Vs[i * 32 + vrow_s][vcol_s]) = vpre[i];
    }
    __syncthreads();
    if (!last) {
      const int tn = t0 + 64;
#pragma unroll
      for (int i = 0; i < 8; ++i) {
        kpre[i] = *(const half8*)(kg + (size_t)(tn + i * 8 + krow_s) * INNER_D + kcol_s);
        vpre[i] = *(const half8*)(vg + (size_t)(i * 32 + vrow_s) * S_LEN + tn + vcol_s);
      }
    }
    // ---- QK^T: one 32x32 tile per wave (rows=pair's 32 s, cols=hw t-half) ----
    v16f sa0 = (v16f)(0.f), sa1 = (v16f)(0.f);
#pragma unroll
    for (int kc = 0; kc < 8; ++kc) {
      half8 kf0 = *(const half8*)(&Ks[hw * 32 + l31][kc * 16 + hl * 8]);
      half8 kf1 = *(const half8*)(&Ks[hw * 32 + l31][(kc + 8) * 16 + hl * 8]);
      sa0 = __builtin_amdgcn_mfma_f32_32x32x16_f16(qf[kc], kf0, sa0, 0, 0, 0);
      sa1 = __builtin_amdgcn_mfma_f32_32x32x16_f16(qf[kc + 8], kf1, sa1, 0, 0, 0);
    }
    v16f sacc = sa0 + sa1;
    // ---- weights + P write ----
    const int t = t0 + tloc;
    const bool diag = last;
    if (diag) {
      const float mt = mp[t];
#pragma unroll
      for (int i = 0; i < 16; ++i) {
        const int srow = s0 + rowl[i];
        float cc = (t <= srow) ? sacc[i] * scale * __expf(mt - rmax_row[i]) : 0.f;
        rsum[i] += cc;
        plds[pair][rowl[i]][tloc] = (_Float16)cc;
      }
    } else {
      const float rtile = rmaxp[t0 + 63];
      const float emv = emp[t];
#pragma unroll
      for (int i = 0; i < 16; ++i) {
        float cc = sacc[i] * emv * __expf(rtile - rmax_row[i]);
        rsum[i] += cc;
        plds[pair][rowl[i]][tloc] = (_Float16)cc;
      }
    }
    __syncthreads();   // P visible to pair partner
    // ---- PV: wave's d-half (128) = 4 tiles of 32 ----
#pragma unroll
    for (int kc = 0; kc < 4; ++kc) {
      half8 pf = *(const half8*)(&plds[pair][l31][kc * 16 + hl * 8]);
#pragma unroll
      for (int dt = 0; dt < 4; ++dt) {
        half8 vf = *(const half8*)(&Vs[hw * 128 + dt * 32 + l31][kc * 16 + hl * 8]);
        acc[dt] = __builtin_amdgcn_mfma_f32_32x32x16_f16(pf, vf, acc[dt], 0, 0, 0);
      }
    }
  }

  // ================= epilogue =================
  // rsum: reduce over the 32 lanes of this half (t-columns of this wave)
#pragma unroll
  for (int i = 0; i < 16; ++i) {
    float x = rsum[i];
    x += __shfl_xor(x, 1); x += __shfl_xor(x, 2); x += __shfl_xor(x, 4);
    x += __shfl_xor(x, 8); x += __shfl_xor(x, 16);
    rsum[i] = x;
  }
  __syncthreads();   // plds P-reads done; safe to reuse as redb
  if (l31 == 0) {
#pragma unroll
    for (int i = 0; i < 16; ++i) redb[(pair * 2 + hw) * 32 + rowl[i]] = rsum[i];
  }
  __syncthreads();
  float inv[16];
#pragma unroll
  for (int i = 0; i < 16; ++i) {
    float tot = redb[(pair * 2 + 0) * 32 + rowl[i]] + redb[(pair * 2 + 1) * 32 + rowl[i]];
    float md = maxdp[s0 + rowl[i]];
    float n = fmaxf(fabsf(tot), __expf(-md));
    inv[i] = 1.f / (n + 1e-6f);
  }
#pragma unroll
  for (int dt = 0; dt < 4; ++dt)
#pragma unroll
    for (int i = 0; i < 16; ++i) acc[dt][i] *= inv[i];
  // mean over 256 d (wave covers 128, pair partner the rest)
  float ps[16];
#pragma unroll
  for (int i = 0; i < 16; ++i) {
    float x = acc[0][i] + acc[1][i] + acc[2][i] + acc[3][i];
    x += __shfl_xor(x, 1); x += __shfl_xor(x, 2); x += __shfl_xor(x, 4);
    x += __shfl_xor(x, 8); x += __shfl_xor(x, 16);
    ps[i] = x;
  }
  __syncthreads();
  if (l31 == 0) {
#pragma unroll
    for (int i = 0; i < 16; ++i) redb[(pair * 2 + hw) * 32 + rowl[i]] = ps[i];
  }
  __syncthreads();
  float meanv[16];
#pragma unroll
  for (int i = 0; i < 16; ++i)
    meanv[i] = (redb[(pair * 2) * 32 + rowl[i]] + redb[(pair * 2 + 1) * 32 + rowl[i]]) * (1.f / DH_D);
  __syncthreads();
  // var
#pragma unroll
  for (int i = 0; i < 16; ++i) {
    float sq = 0.f;
#pragma unroll
    for (int dt = 0; dt < 4; ++dt) { float d = acc[dt][i] - meanv[i]; sq += d * d; }
    sq += __shfl_xor(sq, 1); sq += __shfl_xor(sq, 2); sq += __shfl_xor(sq, 4);
    sq += __shfl_xor(sq, 8); sq += __shfl_xor(sq, 16);
    ps[i] = sq;
  }
  if (l31 == 0) {
#pragma unroll
    for (int i = 0; i < 16; ++i) redb[(pair * 2 + hw) * 32 + rowl[i]] = ps[i];
  }
  __syncthreads();
  float rstdv[16];
#pragma unroll
  for (int i = 0; i < 16; ++i) {
    float v = (redb[(pair * 2) * 32 + rowl[i]] + redb[(pair * 2 + 1) * 32 + rowl[i]]) * (1.f / DH_D);
    rstdv[i] = rsqrtf(v + 1e-5f);
  }
  // store
#pragma unroll
  for (int dt = 0; dt < 4; ++dt) {
    const int d = h * DH_D + hw * 128 + dt * 32 + l31;
    const float w = mhln_w[d];
    const float sk = skip[d];
#pragma unroll
    for (int i = 0; i < 16; ++i) {
      const size_t row = (size_t)(b * S_LEN + s0 + rowl[i]);
      float xcv = (float)xch[row * INNER_D + d];
      float sz = (float)szb[row * INNER_D + d];
      float o = ((acc[dt][i] - meanv[i]) * rstdv[i] * w + sk * xcv) * sz;
      hstate[row * INNER_D + d] = (_Float16)o;
    }
  }
}

// ---------------------------------------------------------------------------
extern "C" void kernel_launch(void* const* d_in, const int* in_sizes, int n_in,
                              void* d_out, int out_size, void* d_ws, size_t ws_size,
                              hipStream_t stream)
{
  const float* x      = (const float*)d_in[0];
  const float* W_in   = (const float*)d_in[1];
  const float* b_in   = (const float*)d_in[2];
  const float* ln1_w  = (const float*)d_in[3];
  const float* W_up   = (const float*)d_in[4];
  const float* conv_w = (const float*)d_in[5];
  const float* conv_b = (const float*)d_in[6];
  const float* Wq     = (const float*)d_in[7];
  const float* Wk     = (const float*)d_in[8];
  const float* Wv     = (const float*)d_in[9];
  const float* W_ig   = (const float*)d_in[10];
  const float* b_ig   = (const float*)d_in[11];
  const float* W_fg   = (const float*)d_in[12];
  const float* b_fg   = (const float*)d_in[13];
  const float* mhln_w = (const float*)d_in[14];
  const float* skip   = (const float*)d_in[15];
  const float* W_down = (const float*)d_in[16];
  const float* ln_post_w = (const float*)d_in[17];
  float* out = (float*)d_out;

  float* ws = (float*)d_ws;
  size_t o = 0;
  float* xp     = ws + o; o += (size_t)NROW * E_DIM;
  float* hbuf   = ws + o; o += (size_t)NROW * E_DIM;
  _Float16* h16 = (_Float16*)(ws + o);
  size_t ho = 0;
  _Float16* xh      = h16 + ho; ho += (size_t)NROW * F_IN_D;
  _Float16* WinH    = h16 + ho; ho += (size_t)E_DIM * F_IN_D;
  _Float16* WupH    = h16 + ho; ho += (size_t)2 * INNER_D * E_DIM;
  _Float16* WdownH  = h16 + ho; ho += (size_t)E_DIM * INNER_D;
  _Float16* hh      = h16 + ho; ho += (size_t)NROW * E_DIM;
  _Float16* xmh     = h16 + ho; ho += (size_t)NROW * INNER_D;
  _Float16* szb     = h16 + ho; ho += (size_t)NROW * INNER_D;
  _Float16* xch     = h16 + ho; ho += (size_t)NROW * INNER_D;
  _Float16* qh      = h16 + ho; ho += (size_t)NROW * INNER_D;
  _Float16* khb     = h16 + ho; ho += (size_t)NROW * INNER_D;
  _Float16* vhb     = h16 + ho; ho += (size_t)NROW * INNER_D;
  _Float16* vtb     = h16 + ho; ho += (size_t)NROW * INNER_D;
  _Float16* hstateH = h16 + ho; ho += (size_t)NROW * INNER_D;

  const int GSZ = B_SZ * NH_D * S_LEN;  // 32768
  float* igb   = hbuf;
  float* fgb   = hbuf + GSZ;
  float* mb    = hbuf + 2 * GSZ;
  float* rmaxb = hbuf + 3 * GSZ;
  float* maxdb = hbuf + 4 * GSZ;
  float* emb   = hbuf + 5 * GSZ;
  float* yb    = hbuf;

  dim3 blk(256);
  const int nx = NROW * F_IN_D, nwi = E_DIM * F_IN_D,
            nwu = 2 * INNER_D * E_DIM, nwd = E_DIM * INNER_D;
  const int ntot = nx + nwi + nwu + nwd;
  cast4_kernel<<<(ntot / 4 + 255) / 256, blk, 0, stream>>>(
      x, W_in, W_up, W_down, xh, WinH, WupH, WdownH, nx, nwi, nwu, nwd);
  gemm_h16<<<dim3(E_DIM / GBN, NROW / GBM), blk, 0, stream>>>(
      xh, WinH, b_in, xp, NROW, E_DIM, F_IN_D);
  ln_mul_kernel<<<NROW, blk, 0, stream>>>(xp, ln1_w, hh);
  gemm_h16_up<<<dim3(2 * INNER_D / GBN, NROW / GBM), blk, 0, stream>>>(
      hh, WupH, xmh, szb, NROW, 2 * INNER_D, E_DIM);
  chg_kernel<<<NROW / 4, blk, 0, stream>>>(
      xmh, conv_w, conv_b, Wq, Wk, Wv, W_ig, b_ig, W_fg, b_fg,
      xch, qh, khb, vhb, igb, fgb);
  scan_kernel<<<B_SZ * NH_D, blk, 0, stream>>>(igb, fgb, mb, rmaxb, maxdb, emb);
  vtrans_kernel<<<dim3(16, 16, 8), blk, 0, stream>>>(vhb, vtb);
  attn32_kernel<<<512, blk, 0, stream>>>(
      qh, khb, vtb, mb, emb, rmaxb, maxdb, mhln_w, skip, xch, szb, hstateH);
  gemm_h16<<<dim3(E_DIM / GBN, NROW / GBM), blk, 0, stream>>>(
      hstateH, WdownH, nullptr, yb, NROW, E_DIM, INNER_D);
  final_ln_kernel<<<NROW, blk, 0, stream>>>(xp, yb, ln_post_w, out);
}

// Round 10
// 283.010 us; speedup vs baseline: 1.1741x; 1.1741x over previous
//
#include <hip/hip_runtime.h>

#define S_LEN 1024
#define B_SZ 8
#define F_IN_D 256
#define E_DIM 512
#define INNER_D 1024
#define NH_D 4
#define DH_D 256
#define NROW (B_SZ * S_LEN)   // 8192

typedef _Float16 half8 __attribute__((ext_vector_type(8)));
typedef _Float16 half4_t __attribute__((ext_vector_type(4)));
typedef float v4f __attribute__((ext_vector_type(4)));

// ---------------------------------------------------------------------------
// Cast 4 f32 buffers to f16 in one pass (x, W_in, W_up, W_down).
// ---------------------------------------------------------------------------
__global__ __launch_bounds__(256) void cast4_kernel(
    const float* __restrict__ s0, const float* __restrict__ s1,
    const float* __restrict__ s2, const float* __restrict__ s3,
    _Float16* __restrict__ d0, _Float16* __restrict__ d1,
    _Float16* __restrict__ d2, _Float16* __restrict__ d3,
    int n0, int n1, int n2, int n3)
{
  int i = (blockIdx.x * 256 + threadIdx.x) * 4;
  const float* s; _Float16* d; int off;
  if (i < n0)                { s = s0; d = d0; off = i; }
  else if (i < n0 + n1)      { s = s1; d = d1; off = i - n0; }
  else if (i < n0 + n1 + n2) { s = s2; d = d2; off = i - n0 - n1; }
  else if (i < n0 + n1 + n2 + n3) { s = s3; d = d3; off = i - n0 - n1 - n2; }
  else return;
  float4 v = *(const float4*)(s + off);
  half4_t o = {(_Float16)v.x, (_Float16)v.y, (_Float16)v.z, (_Float16)v.w};
  *(half4_t*)(d + off) = o;
}

// ---------------------------------------------------------------------------
// Pure-f16 MFMA NT GEMM: C[M,N] = A[M,K] @ B[N,K]^T (+ bias), C f32.
// 128x128 tile, BK=64 (half the barrier drains of BK=32). M%128, N%128, K%64.
// ---------------------------------------------------------------------------
#define GBM 128
#define GBN 128
#define GBK 64
#define LDKG (GBK + 8)   // 72 halves = 36 dwords stride

__global__ __launch_bounds__(256) void gemm_h16(
    const _Float16* __restrict__ A, const _Float16* __restrict__ B,
    const float* __restrict__ bias, float* __restrict__ C,
    int M, int N, int K)
{
  __shared__ __align__(16) _Float16 As[GBM][LDKG];
  __shared__ __align__(16) _Float16 Bs[GBN][LDKG];
  const int tid = threadIdx.x;
  const int lane = tid & 63, w = tid >> 6;
  const int wr = w >> 1, wc = w & 1;
  const int quad = lane >> 4, l16 = lane & 15;
  const int bm = blockIdx.y * GBM, bn = blockIdx.x * GBN;
  const int srow = tid >> 1;          // 0..127
  const int scol = (tid & 1) * 32;    // halves

  v4f acc[4][4];
#pragma unroll
  for (int i = 0; i < 4; ++i)
#pragma unroll
    for (int j = 0; j < 4; ++j) acc[i][j] = (v4f){0.f, 0.f, 0.f, 0.f};

  const _Float16* Ap = A + (size_t)(bm + srow) * K + scol;
  const _Float16* Bp = B + (size_t)(bn + srow) * K + scol;
  half8 ap[4], bp[4];
#pragma unroll
  for (int j = 0; j < 4; ++j) {
    ap[j] = *(const half8*)(Ap + j * 8);
    bp[j] = *(const half8*)(Bp + j * 8);
  }

  for (int k0 = 0; k0 < K; k0 += GBK) {
    __syncthreads();
#pragma unroll
    for (int j = 0; j < 4; ++j) {
      *(half8*)(&As[srow][scol + j * 8]) = ap[j];
      *(half8*)(&Bs[srow][scol + j * 8]) = bp[j];
    }
    __syncthreads();
    if (k0 + GBK < K) {
      const int kn = k0 + GBK;
#pragma unroll
      for (int j = 0; j < 4; ++j) {
        ap[j] = *(const half8*)(Ap + kn + j * 8);
        bp[j] = *(const half8*)(Bp + kn + j * 8);
      }
    }
#pragma unroll
    for (int kc = 0; kc < 2; ++kc) {
      half8 af[4], bf[4];
#pragma unroll
      for (int i = 0; i < 4; ++i)
        af[i] = *(const half8*)(&As[wr * 64 + i * 16 + l16][kc * 32 + quad * 8]);
#pragma unroll
      for (int j = 0; j < 4; ++j)
        bf[j] = *(const half8*)(&Bs[wc * 64 + j * 16 + l16][kc * 32 + quad * 8]);
#pragma unroll
      for (int i = 0; i < 4; ++i)
#pragma unroll
        for (int j = 0; j < 4; ++j)
          acc[i][j] = __builtin_amdgcn_mfma_f32_16x16x32_f16(af[i], bf[j], acc[i][j], 0, 0, 0);
    }
  }

#pragma unroll
  for (int j = 0; j < 4; ++j) {
    const int col = bn + wc * 64 + j * 16 + l16;
    const float bv = bias ? bias[col] : 0.f;
#pragma unroll
    for (int i = 0; i < 4; ++i) {
      const int row0 = bm + wr * 64 + i * 16 + quad * 4;
#pragma unroll
      for (int r = 0; r < 4; ++r)
        C[(size_t)(row0 + r) * N + col] = acc[i][j][r] + bv;
    }
  }
}

// ---------------------------------------------------------------------------
// Up-projection GEMM (BK=64): writes x_m half as f16 (xmh), silu(z) f16 (szb).
// ---------------------------------------------------------------------------
__global__ __launch_bounds__(256) void gemm_h16_up(
    const _Float16* __restrict__ A, const _Float16* __restrict__ B,
    _Float16* __restrict__ xmh, _Float16* __restrict__ szb,
    int M, int N, int K)
{
  __shared__ __align__(16) _Float16 As[GBM][LDKG];
  __shared__ __align__(16) _Float16 Bs[GBN][LDKG];
  const int tid = threadIdx.x;
  const int lane = tid & 63, w = tid >> 6;
  const int wr = w >> 1, wc = w & 1;
  const int quad = lane >> 4, l16 = lane & 15;
  const int bm = blockIdx.y * GBM, bn = blockIdx.x * GBN;
  const int srow = tid >> 1;
  const int scol = (tid & 1) * 32;

  v4f acc[4][4];
#pragma unroll
  for (int i = 0; i < 4; ++i)
#pragma unroll
    for (int j = 0; j < 4; ++j) acc[i][j] = (v4f){0.f, 0.f, 0.f, 0.f};

  const _Float16* Ap = A + (size_t)(bm + srow) * K + scol;
  const _Float16* Bp = B + (size_t)(bn + srow) * K + scol;
  half8 ap[4], bp[4];
#pragma unroll
  for (int j = 0; j < 4; ++j) {
    ap[j] = *(const half8*)(Ap + j * 8);
    bp[j] = *(const half8*)(Bp + j * 8);
  }

  for (int k0 = 0; k0 < K; k0 += GBK) {
    __syncthreads();
#pragma unroll
    for (int j = 0; j < 4; ++j) {
      *(half8*)(&As[srow][scol + j * 8]) = ap[j];
      *(half8*)(&Bs[srow][scol + j * 8]) = bp[j];
    }
    __syncthreads();
    if (k0 + GBK < K) {
      const int kn = k0 + GBK;
#pragma unroll
      for (int j = 0; j < 4; ++j) {
        ap[j] = *(const half8*)(Ap + kn + j * 8);
        bp[j] = *(const half8*)(Bp + kn + j * 8);
      }
    }
#pragma unroll
    for (int kc = 0; kc < 2; ++kc) {
      half8 af[4], bf[4];
#pragma unroll
      for (int i = 0; i < 4; ++i)
        af[i] = *(const half8*)(&As[wr * 64 + i * 16 + l16][kc * 32 + quad * 8]);
#pragma unroll
      for (int j = 0; j < 4; ++j)
        bf[j] = *(const half8*)(&Bs[wc * 64 + j * 16 + l16][kc * 32 + quad * 8]);
#pragma unroll
      for (int i = 0; i < 4; ++i)
#pragma unroll
        for (int j = 0; j < 4; ++j)
          acc[i][j] = __builtin_amdgcn_mfma_f32_16x16x32_f16(af[i], bf[j], acc[i][j], 0, 0, 0);
    }
  }

  const bool zhalf = (bn >= INNER_D);
#pragma unroll
  for (int j = 0; j < 4; ++j) {
    const int col = bn + wc * 64 + j * 16 + l16;
    const int colm = col & (INNER_D - 1);
#pragma unroll
    for (int i = 0; i < 4; ++i) {
      const int row0 = bm + wr * 64 + i * 16 + quad * 4;
#pragma unroll
      for (int r = 0; r < 4; ++r) {
        float a = acc[i][j][r];
        if (zhalf) {
          float s = a / (1.f + __expf(-a));
          szb[(size_t)(row0 + r) * INNER_D + colm] = (_Float16)s;
        } else {
          xmh[(size_t)(row0 + r) * INNER_D + colm] = (_Float16)a;
        }
      }
    }
  }
}

// ---------------------------------------------------------------------------
__device__ __forceinline__ float block_sum4(float v, float* red, int tid) {
#pragma unroll
  for (int off = 32; off; off >>= 1) v += __shfl_xor(v, off);
  if ((tid & 63) == 0) red[tid >> 6] = v;
  __syncthreads();
  float t = red[0] + red[1] + red[2] + red[3];
  __syncthreads();
  return t;
}

__global__ __launch_bounds__(256) void ln_mul_kernel(
    const float* __restrict__ in, const float* __restrict__ w,
    _Float16* __restrict__ out)
{
  __shared__ float red[4];
  const int row = blockIdx.x;
  const int tid = threadIdx.x;
  const float* p = in + (size_t)row * E_DIM;
  float v0 = p[tid], v1 = p[tid + 256];
  float mean = block_sum4(v0 + v1, red, tid) * (1.f / E_DIM);
  float d0 = v0 - mean, d1 = v1 - mean;
  float var = block_sum4(d0 * d0 + d1 * d1, red, tid) * (1.f / E_DIM);
  float rstd = rsqrtf(var + 1e-5f);
  out[(size_t)row * E_DIM + tid] = (_Float16)(d0 * rstd * w[tid]);
  out[(size_t)row * E_DIM + tid + 256] = (_Float16)(d1 * rstd * w[tid + 256]);
}

__global__ __launch_bounds__(256) void final_ln_kernel(
    const float* __restrict__ res, const float* __restrict__ y,
    const float* __restrict__ w, float* __restrict__ out)
{
  __shared__ float red[4];
  const int row = blockIdx.x;
  const int tid = threadIdx.x;
  const size_t base = (size_t)row * E_DIM;
  float v0 = res[base + tid] + y[base + tid];
  float v1 = res[base + tid + 256] + y[base + tid + 256];
  float mean = block_sum4(v0 + v1, red, tid) * (1.f / E_DIM);
  float d0 = v0 - mean, d1 = v1 - mean;
  float var = block_sum4(d0 * d0 + d1 * d1, red, tid) * (1.f / E_DIM);
  float rstd = rsqrtf(var + 1e-5f);
  out[base + tid] = d0 * rstd * w[tid];
  out[base + tid + 256] = d1 * rstd * w[tid + 256];
}

// ---------------------------------------------------------------------------
// Fused conv+silu + headwise q/k/v + gates, 4 rows per block.
// ---------------------------------------------------------------------------
__global__ __launch_bounds__(256) void chg_kernel(
    const _Float16* __restrict__ xm, const float* __restrict__ cw,
    const float* __restrict__ cb,
    const float* __restrict__ Wq, const float* __restrict__ Wk,
    const float* __restrict__ Wv,
    const float* __restrict__ Wig, const float* __restrict__ big,
    const float* __restrict__ Wfg, const float* __restrict__ bfg,
    _Float16* __restrict__ xch, _Float16* __restrict__ qh,
    _Float16* __restrict__ khb, _Float16* __restrict__ vhb,
    float* __restrict__ ig, float* __restrict__ fg)
{
  __shared__ float red[4][32];
  const int tid = threadIdx.x;
  const int lane = tid & 63, wid = tid >> 6;
  const int row0 = blockIdx.x * 4;
  const int sl0 = row0 & (S_LEN - 1);
  const int c = tid * 4;

  float t[7][4];
#pragma unroll
  for (int j = 0; j < 7; ++j) {
    const int off = j - 3;
    if (sl0 + off < 0) {
      t[j][0] = t[j][1] = t[j][2] = t[j][3] = 0.f;
    } else {
      half4_t hv = *(const half4_t*)(xm + (size_t)(row0 + off) * INNER_D + c);
      t[j][0] = (float)hv.x; t[j][1] = (float)hv.y;
      t[j][2] = (float)hv.z; t[j][3] = (float)hv.w;
    }
  }
  float wct[4][4];
#pragma unroll
  for (int j = 0; j < 4; ++j) {
    float4 wc4 = *(const float4*)(cw + (c + j) * 4);
    wct[j][0] = wc4.x; wct[j][1] = wc4.y; wct[j][2] = wc4.z; wct[j][3] = wc4.w;
  }
  float4 cb4 = *(const float4*)(cb + c);
  const float cbs[4] = {cb4.x, cb4.y, cb4.z, cb4.w};
  float wqm[16], wkm[16], wvm[16];
#pragma unroll
  for (int i = 0; i < 4; ++i) {
    float4 a = *(const float4*)(Wq + tid * 16 + i * 4);
    float4 bq = *(const float4*)(Wk + tid * 16 + i * 4);
    float4 cq = *(const float4*)(Wv + tid * 16 + i * 4);
    wqm[i * 4] = a.x; wqm[i * 4 + 1] = a.y; wqm[i * 4 + 2] = a.z; wqm[i * 4 + 3] = a.w;
    wkm[i * 4] = bq.x; wkm[i * 4 + 1] = bq.y; wkm[i * 4 + 2] = bq.z; wkm[i * 4 + 3] = bq.w;
    wvm[i * 4] = cq.x; wvm[i * 4 + 1] = cq.y; wvm[i * 4 + 2] = cq.z; wvm[i * 4 + 3] = cq.w;
  }

  float q4[4][4], k4[4][4], v4m[4][4];
#pragma unroll
  for (int r = 0; r < 4; ++r) {
    float xc4[4];
#pragma unroll
    for (int j = 0; j < 4; ++j) {
      float a = cbs[j] + wct[j][0] * t[r][j] + wct[j][1] * t[r + 1][j]
                       + wct[j][2] * t[r + 2][j] + wct[j][3] * t[r + 3][j];
      xc4[j] = a / (1.f + __expf(-a));
    }
#pragma unroll
    for (int i = 0; i < 4; ++i) {
      q4[r][i] = wqm[i * 4] * xc4[0] + wqm[i * 4 + 1] * xc4[1]
               + wqm[i * 4 + 2] * xc4[2] + wqm[i * 4 + 3] * xc4[3];
      k4[r][i] = wkm[i * 4] * xc4[0] + wkm[i * 4 + 1] * xc4[1]
               + wkm[i * 4 + 2] * xc4[2] + wkm[i * 4 + 3] * xc4[3];
      v4m[r][i] = wvm[i * 4] * t[r + 3][0] + wvm[i * 4 + 1] * t[r + 3][1]
                + wvm[i * 4 + 2] * t[r + 3][2] + wvm[i * 4 + 3] * t[r + 3][3];
    }
    const size_t base = (size_t)(row0 + r) * INNER_D + c;
    half4_t xo = {(_Float16)xc4[0], (_Float16)xc4[1], (_Float16)xc4[2], (_Float16)xc4[3]};
    half4_t qo = {(_Float16)q4[r][0], (_Float16)q4[r][1], (_Float16)q4[r][2], (_Float16)q4[r][3]};
    half4_t ko = {(_Float16)k4[r][0], (_Float16)k4[r][1], (_Float16)k4[r][2], (_Float16)k4[r][3]};
    half4_t vo = {(_Float16)v4m[r][0], (_Float16)v4m[r][1], (_Float16)v4m[r][2], (_Float16)v4m[r][3]};
    *(half4_t*)(xch + base) = xo;
    *(half4_t*)(qh + base) = qo;
    *(half4_t*)(khb + base) = ko;
    *(half4_t*)(vhb + base) = vo;
  }

  float vals[32];
#pragma unroll
  for (int g = 0; g < 8; ++g) {
    const float* wb = (g < 4 ? Wig : Wfg) + (g & 3) * 3072 + c;
    float4 w1 = *(const float4*)(wb);
    float4 w2 = *(const float4*)(wb + 1024);
    float4 w3 = *(const float4*)(wb + 2048);
#pragma unroll
    for (int r = 0; r < 4; ++r) {
      vals[g * 4 + r] =
          q4[r][0] * w1.x + q4[r][1] * w1.y + q4[r][2] * w1.z + q4[r][3] * w1.w
        + k4[r][0] * w2.x + k4[r][1] * w2.y + k4[r][2] * w2.z + k4[r][3] * w2.w
        + v4m[r][0] * w3.x + v4m[r][1] * w3.y + v4m[r][2] * w3.z + v4m[r][3] * w3.w;
    }
  }
#pragma unroll
  for (int i = 0; i < 32; ++i) {
    float x = vals[i];
#pragma unroll
    for (int off = 32; off; off >>= 1) x += __shfl_xor(x, off);
    vals[i] = x;
  }
  if (lane == 0) {
#pragma unroll
    for (int i = 0; i < 32; ++i) red[wid][i] = vals[i];
  }
  __syncthreads();
  if (tid < 32) {
    float sm = red[0][tid] + red[1][tid] + red[2][tid] + red[3][tid];
    const int g = tid >> 2, r = tid & 3;
    const int h = g & 3;
    const int b = row0 >> 10;
    const size_t oidx = (size_t)(b * NH_D + h) * S_LEN + sl0 + r;
    if (g < 4) ig[oidx] = sm + big[h];
    else       fg[oidx] = sm + bfg[h];
  }
}

// ---------------------------------------------------------------------------
__device__ __forceinline__ float logsigf(float x) {
  return fminf(x, 0.f) - log1pf(__expf(-fabsf(x)));
}

__global__ __launch_bounds__(256) void scan_kernel(
    const float* __restrict__ ig, const float* __restrict__ fg,
    float* __restrict__ m_, float* __restrict__ rmax_, float* __restrict__ maxd_,
    float* __restrict__ em_)
{
  __shared__ float sc[256];
  const int bh = blockIdx.x;
  const int tid = threadIdx.x;
  const size_t base = (size_t)bh * S_LEN + tid * 4;
  float4 f4 = *(const float4*)(fg + base);
  float4 i4 = *(const float4*)(ig + base);
  float l0 = logsigf(f4.x), l1 = logsigf(f4.y), l2 = logsigf(f4.z), l3 = logsigf(f4.w);
  float p0 = l0, p1 = p0 + l1, p2 = p1 + l2, p3 = p2 + l3;
  sc[tid] = p3;
  __syncthreads();
  for (int off = 1; off < 256; off <<= 1) {
    float o = (tid >= off) ? sc[tid - off] : 0.f;
    __syncthreads();
    sc[tid] += o;
    __syncthreads();
  }
  float aoff = (tid == 0) ? 0.f : sc[tid - 1];
  __syncthreads();
  float a0 = aoff + p0, a1 = aoff + p1, a2 = aoff + p2, a3 = aoff + p3;
  float m0 = i4.x - a0, m1 = i4.y - a1, m2 = i4.z - a2, m3 = i4.w - a3;
  float x0 = m0, x1 = fmaxf(x0, m1), x2 = fmaxf(x1, m2), x3 = fmaxf(x2, m3);
  sc[tid] = x3;
  __syncthreads();
  for (int off = 1; off < 256; off <<= 1) {
    float o = (tid >= off) ? sc[tid - off] : -1e30f;
    __syncthreads();
    sc[tid] = fmaxf(sc[tid], o);
    __syncthreads();
  }
  float moff = (tid == 0) ? -1e30f : sc[tid - 1];
  float tmax = sc[tid | 15];
  float r0 = fmaxf(moff, x0), r1 = fmaxf(moff, x1), r2 = fmaxf(moff, x2), r3 = fmaxf(moff, x3);
  const float scale = 0.0625f;
  float4 mo = {m0, m1, m2, m3};
  float4 ro = {r0, r1, r2, r3};
  float4 dd = {a0 + r0, a1 + r1, a2 + r2, a3 + r3};
  float4 eo = {scale * __expf(m0 - tmax), scale * __expf(m1 - tmax),
               scale * __expf(m2 - tmax), scale * __expf(m3 - tmax)};
  *(float4*)(m_ + base) = mo;
  *(float4*)(rmax_ + base) = ro;
  *(float4*)(maxd_ + base) = dd;
  *(float4*)(em_ + base) = eo;
}

// ---------------------------------------------------------------------------
__global__ __launch_bounds__(256) void vtrans_kernel(
    const _Float16* __restrict__ vb, _Float16* __restrict__ vt)
{
  __shared__ _Float16 tile[64][68];
  const int b = blockIdx.z, dt = blockIdx.x, st = blockIdx.y;
  const int c4 = (threadIdx.x & 15) * 4, rr = threadIdx.x >> 4;
  const int s0 = st * 64, d0 = dt * 64;
#pragma unroll
  for (int i = 0; i < 4; ++i) {
    int r = rr + i * 16;
    half4_t v = *(const half4_t*)(vb + ((size_t)(b * S_LEN + s0 + r)) * INNER_D + d0 + c4);
    tile[r][c4 + 0] = v.x; tile[r][c4 + 1] = v.y;
    tile[r][c4 + 2] = v.z; tile[r][c4 + 3] = v.w;
  }
  __syncthreads();
#pragma unroll
  for (int i = 0; i < 4; ++i) {
    int dd = rr + i * 16;
    half4_t o = {tile[c4 + 0][dd], tile[c4 + 1][dd], tile[c4 + 2][dd], tile[c4 + 3][dd]};
    *(half4_t*)(vt + ((size_t)(b * INNER_D + d0 + dd)) * S_LEN + s0 + c4) = o;
  }
}

// ---------------------------------------------------------------------------
// Block-cooperative LDS-staged MFMA attention (R8 16x16 version, reverted).
// ---------------------------------------------------------------------------
#define KP 264
#define VP 72

__global__ __launch_bounds__(256, 2) void attn_blk_kernel(
    const _Float16* __restrict__ qh, const _Float16* __restrict__ khb,
    const _Float16* __restrict__ vt,
    const float* __restrict__ m_, const float* __restrict__ em,
    const float* __restrict__ rmax_, const float* __restrict__ maxd_,
    const float* __restrict__ mhln_w, const float* __restrict__ skip,
    const _Float16* __restrict__ xch, const _Float16* __restrict__ szb,
    _Float16* __restrict__ hstate)
{
  __shared__ __align__(16) _Float16 Ks[64][KP];
  __shared__ __align__(16) _Float16 Vs[256][VP];
  __shared__ _Float16 plds[4][16][72];
  const int tid = threadIdx.x;
  const int lane = tid & 63, wid = tid >> 6;
  const int quad = lane >> 4, l16 = lane & 15;
  const int bh = blockIdx.x & 31;
  const int pp = blockIdx.x >> 5;
  const int sblk = 15 - pp;
  const int h = bh & 3, b = bh >> 2;
  _Float16 (*P)[72] = plds[wid];
  const float* rmaxp = rmax_ + (size_t)bh * S_LEN;
  const float* emp = em + (size_t)bh * S_LEN;
  const float* mp = m_ + (size_t)bh * S_LEN;
  const float* maxdp = maxd_ + (size_t)bh * S_LEN;
  const float scale = 0.0625f;

  const _Float16* kg = khb + ((size_t)(b * S_LEN)) * INNER_D + h * DH_D;
  const _Float16* vg = vt + ((size_t)(b * INNER_D + h * DH_D)) * S_LEN;
  const int krow_s = tid >> 5;
  const int kcol_s = (tid & 31) * 8;
  const int vrow_s = tid >> 3;
  const int vcol_s = (tid & 7) * 8;

  const int ntile = sblk + 1;
  const int s0 = sblk * 64 + wid * 16;

  half8 kpre[8], vpre[8];
#pragma unroll
  for (int i = 0; i < 8; ++i) {
    kpre[i] = *(const half8*)(kg + (size_t)(i * 8 + krow_s) * INNER_D + kcol_s);
    vpre[i] = *(const half8*)(vg + (size_t)(i * 32 + vrow_s) * S_LEN + vcol_s);
  }

  half8 qf[8];
  const _Float16* qrow = qh + ((size_t)(b * S_LEN + s0 + l16)) * INNER_D + h * DH_D + quad * 8;
#pragma unroll
  for (int c = 0; c < 8; ++c) qf[c] = *(const half8*)(qrow + c * 32);

  v4f acc[16];
#pragma unroll
  for (int nc = 0; nc < 16; ++nc) acc[nc] = (v4f){0.f, 0.f, 0.f, 0.f};
  float rsum[4] = {0.f, 0.f, 0.f, 0.f};
  float rmax_row[4];
#pragma unroll
  for (int r = 0; r < 4; ++r) rmax_row[r] = rmaxp[s0 + quad * 4 + r];

  for (int tt = 0; tt < ntile; ++tt) {
    const int t0 = tt * 64;
    const bool last = (tt + 1 == ntile);
    __syncthreads();
#pragma unroll
    for (int i = 0; i < 8; ++i) {
      *(half8*)(&Ks[i * 8 + krow_s][kcol_s]) = kpre[i];
      *(half8*)(&Vs[i * 32 + vrow_s][vcol_s]) = vpre[i];
    }
    __syncthreads();
    if (!last) {
      const int tn = t0 + 64;
#pragma unroll
      for (int i = 0; i < 8; ++i) {
        kpre[i] = *(const half8*)(kg + (size_t)(tn + i * 8 + krow_s) * INNER_D + kcol_s);
        vpre[i] = *(const half8*)(vg + (size_t)(i * 32 + vrow_s) * S_LEN + tn + vcol_s);
      }
    }
    const bool diag = last;
    float rowfac[4];
    if (!diag) {
      const float rtile = rmaxp[t0 + 63];
#pragma unroll
      for (int r = 0; r < 4; ++r) rowfac[r] = __expf(rtile - rmax_row[r]);
    }
#pragma unroll
    for (int sub = 0; sub < 4; ++sub) {
      v4f sacc0 = (v4f){0.f, 0.f, 0.f, 0.f};
      v4f sacc1 = (v4f){0.f, 0.f, 0.f, 0.f};
#pragma unroll
      for (int c = 0; c < 4; ++c) {
        half8 kf0 = *(const half8*)(&Ks[sub * 16 + l16][c * 32 + quad * 8]);
        half8 kf1 = *(const half8*)(&Ks[sub * 16 + l16][(c + 4) * 32 + quad * 8]);
        sacc0 = __builtin_amdgcn_mfma_f32_16x16x32_f16(qf[c], kf0, sacc0, 0, 0, 0);
        sacc1 = __builtin_amdgcn_mfma_f32_16x16x32_f16(qf[c + 4], kf1, sacc1, 0, 0, 0);
      }
      v4f sacc = sacc0 + sacc1;
      const int t = t0 + sub * 16 + l16;
      if (diag) {
        const float mt = mp[t];
#pragma unroll
        for (int r = 0; r < 4; ++r) {
          const int srow = s0 + quad * 4 + r;
          float cc = (t <= srow) ? sacc[r] * scale * __expf(mt - rmax_row[r]) : 0.f;
          rsum[r] += cc;
          P[quad * 4 + r][sub * 16 + l16] = (_Float16)cc;
        }
      } else {
        const float emv = emp[t];
#pragma unroll
        for (int r = 0; r < 4; ++r) {
          float cc = sacc[r] * emv * rowfac[r];
          rsum[r] += cc;
          P[quad * 4 + r][sub * 16 + l16] = (_Float16)cc;
        }
      }
    }
    asm volatile("s_waitcnt lgkmcnt(0)" ::: "memory");
    half8 pf0 = *(const half8*)(&P[l16][quad * 8]);
    half8 pf1 = *(const half8*)(&P[l16][32 + quad * 8]);
#pragma unroll
    for (int nc = 0; nc < 16; ++nc) {
      half8 vf0 = *(const half8*)(&Vs[nc * 16 + l16][quad * 8]);
      half8 vf1 = *(const half8*)(&Vs[nc * 16 + l16][32 + quad * 8]);
      acc[nc] = __builtin_amdgcn_mfma_f32_16x16x32_f16(pf0, vf0, acc[nc], 0, 0, 0);
      acc[nc] = __builtin_amdgcn_mfma_f32_16x16x32_f16(pf1, vf1, acc[nc], 0, 0, 0);
    }
  }

  float inv[4];
#pragma unroll
  for (int r = 0; r < 4; ++r) {
    float rs = rsum[r];
    rs += __shfl_xor(rs, 1); rs += __shfl_xor(rs, 2);
    rs += __shfl_xor(rs, 4); rs += __shfl_xor(rs, 8);
    float md = maxdp[s0 + quad * 4 + r];
    float n = fmaxf(fabsf(rs), __expf(-md));
    inv[r] = 1.f / (n + 1e-6f);
  }
#pragma unroll
  for (int nc = 0; nc < 16; ++nc) {
#pragma unroll
    for (int r = 0; r < 4; ++r) acc[nc][r] *= inv[r];
  }
  float mean[4], rstd[4];
#pragma unroll
  for (int r = 0; r < 4; ++r) {
    float sm = 0.f;
#pragma unroll
    for (int nc = 0; nc < 16; ++nc) sm += acc[nc][r];
    sm += __shfl_xor(sm, 1); sm += __shfl_xor(sm, 2);
    sm += __shfl_xor(sm, 4); sm += __shfl_xor(sm, 8);
    mean[r] = sm * (1.f / DH_D);
  }
#pragma unroll
  for (int r = 0; r < 4; ++r) {
    float sq = 0.f;
#pragma unroll
    for (int nc = 0; nc < 16; ++nc) { float d = acc[nc][r] - mean[r]; sq += d * d; }
    sq += __shfl_xor(sq, 1); sq += __shfl_xor(sq, 2);
    sq += __shfl_xor(sq, 4); sq += __shfl_xor(sq, 8);
    rstd[r] = rsqrtf(sq * (1.f / DH_D) + 1e-5f);
  }
#pragma unroll
  for (int nc = 0; nc < 16; ++nc) {
    const int d = h * DH_D + nc * 16 + l16;
    const float w = mhln_w[d];
    const float sk = skip[d];
#pragma unroll
    for (int r = 0; r < 4; ++r) {
      const size_t row = (size_t)(b * S_LEN + s0 + quad * 4 + r);
      float xcv = (float)xch[row * INNER_D + d];
      float sz = (float)szb[row * INNER_D + d];
      float o = ((acc[nc][r] - mean[r]) * rstd[r] * w + sk * xcv) * sz;
      hstate[row * INNER_D + d] = (_Float16)o;
    }
  }
}

// ---------------------------------------------------------------------------
extern "C" void kernel_launch(void* const* d_in, const int* in_sizes, int n_in,
                              void* d_out, int out_size, void* d_ws, size_t ws_size,
                              hipStream_t stream)
{
  const float* x      = (const float*)d_in[0];
  const float* W_in   = (const float*)d_in[1];
  const float* b_in   = (const float*)d_in[2];
  const float* ln1_w  = (const float*)d_in[3];
  const float* W_up   = (const float*)d_in[4];
  const float* conv_w = (const float*)d_in[5];
  const float* conv_b = (const float*)d_in[6];
  const float* Wq     = (const float*)d_in[7];
  const float* Wk     = (const float*)d_in[8];
  const float* Wv     = (const float*)d_in[9];
  const float* W_ig   = (const float*)d_in[10];
  const float* b_ig   = (const float*)d_in[11];
  const float* W_fg   = (const float*)d_in[12];
  const float* b_fg   = (const float*)d_in[13];
  const float* mhln_w = (const float*)d_in[14];
  const float* skip   = (const float*)d_in[15];
  const float* W_down = (const float*)d_in[16];
  const float* ln_post_w = (const float*)d_in[17];
  float* out = (float*)d_out;

  float* ws = (float*)d_ws;
  size_t o = 0;
  float* xp     = ws + o; o += (size_t)NROW * E_DIM;
  float* hbuf   = ws + o; o += (size_t)NROW * E_DIM;
  _Float16* h16 = (_Float16*)(ws + o);
  size_t ho = 0;
  _Float16* xh      = h16 + ho; ho += (size_t)NROW * F_IN_D;
  _Float16* WinH    = h16 + ho; ho += (size_t)E_DIM * F_IN_D;
  _Float16* WupH    = h16 + ho; ho += (size_t)2 * INNER_D * E_DIM;
  _Float16* WdownH  = h16 + ho; ho += (size_t)E_DIM * INNER_D;
  _Float16* hh      = h16 + ho; ho += (size_t)NROW * E_DIM;
  _Float16* xmh     = h16 + ho; ho += (size_t)NROW * INNER_D;
  _Float16* szb     = h16 + ho; ho += (size_t)NROW * INNER_D;
  _Float16* xch     = h16 + ho; ho += (size_t)NROW * INNER_D;
  _Float16* qh      = h16 + ho; ho += (size_t)NROW * INNER_D;
  _Float16* khb     = h16 + ho; ho += (size_t)NROW * INNER_D;
  _Float16* vhb     = h16 + ho; ho += (size_t)NROW * INNER_D;
  _Float16* vtb     = h16 + ho; ho += (size_t)NROW * INNER_D;
  _Float16* hstateH = h16 + ho; ho += (size_t)NROW * INNER_D;

  const int GSZ = B_SZ * NH_D * S_LEN;  // 32768
  float* igb   = hbuf;
  float* fgb   = hbuf + GSZ;
  float* mb    = hbuf + 2 * GSZ;
  float* rmaxb = hbuf + 3 * GSZ;
  float* maxdb = hbuf + 4 * GSZ;
  float* emb   = hbuf + 5 * GSZ;
  float* yb    = hbuf;

  dim3 blk(256);
  const int nx = NROW * F_IN_D, nwi = E_DIM * F_IN_D,
            nwu = 2 * INNER_D * E_DIM, nwd = E_DIM * INNER_D;
  const int ntot = nx + nwi + nwu + nwd;
  cast4_kernel<<<(ntot / 4 + 255) / 256, blk, 0, stream>>>(
      x, W_in, W_up, W_down, xh, WinH, WupH, WdownH, nx, nwi, nwu, nwd);
  gemm_h16<<<dim3(E_DIM / GBN, NROW / GBM), blk, 0, stream>>>(
      xh, WinH, b_in, xp, NROW, E_DIM, F_IN_D);
  ln_mul_kernel<<<NROW, blk, 0, stream>>>(xp, ln1_w, hh);
  gemm_h16_up<<<dim3(2 * INNER_D / GBN, NROW / GBM), blk, 0, stream>>>(
      hh, WupH, xmh, szb, NROW, 2 * INNER_D, E_DIM);
  chg_kernel<<<NROW / 4, blk, 0, stream>>>(
      xmh, conv_w, conv_b, Wq, Wk, Wv, W_ig, b_ig, W_fg, b_fg,
      xch, qh, khb, vhb, igb, fgb);
  scan_kernel<<<B_SZ * NH_D, blk, 0, stream>>>(igb, fgb, mb, rmaxb, maxdb, emb);
  vtrans_kernel<<<dim3(16, 16, 8), blk, 0, stream>>>(vhb, vtb);
  attn_blk_kernel<<<512, blk, 0, stream>>>(
      qh, khb, vtb, mb, emb, rmaxb, maxdb, mhln_w, skip, xch, szb, hstateH);
  gemm_h16<<<dim3(E_DIM / GBN, NROW / GBM), blk, 0, stream>>>(
      hstateH, WdownH, nullptr, yb, NROW, E_DIM, INNER_D);
  final_ln_kernel<<<NROW, blk, 0, stream>>>(xp, yb, ln_post_w, out);
}